// Round 9
// baseline (433.397 us; speedup 1.0000x reference)
//
#include <hip/hip_runtime.h>

// GraphSAGE 2-layer forward, MI355X. Round 9:
//  - XCD-PINNED gather windows: window = blockIdx&7 -> each XCD processes one
//    feature-window for all nodes (slice loaded once chip-wide, L2-resident).
//    gather1: 8 windows x 40 feats (x-region is 320 wide incl. zero pad).
//    gather2: 8 windows x 32 feats.
//  - GEMMs: 1D grid, n-fastest + xcd_swz -> each XCD owns contiguous m-panels
//    (A-panel fetched once chip-wide).
// A1b[20000][640] f16 = [x(300) | 0(20) | agg(300) | 0(20)]
// h1 = relu(A1b @ Wt1^T + b1) (f16)
// [t2 | self] = h1 @ [Wn2^T | Ws2^T]; out = mean_agg(t2) + self

typedef _Float16 f16;
typedef _Float16 f16x4 __attribute__((ext_vector_type(4)));
typedef _Float16 f16x8 __attribute__((ext_vector_type(8)));
typedef float f32x4 __attribute__((ext_vector_type(4)));

constexpr int NN = 20000;   // nodes
constexpr int NE = 640000;  // edges
constexpr int F0 = 300;     // in feats
constexpr int F1 = 512;     // hidden
constexpr int F2 = 256;     // classes
constexpr int KP1 = 640;    // padded concat-K for layer 1
constexpr int XOFF = 320;   // agg region start inside A1b row

// bijective XCD-contiguous swizzle (m204)
__device__ __forceinline__ int xcd_swz(int b, int nb) {
    int xcd = b & 7, loc = b >> 3;
    int q = nb >> 3, r = nb & 7;
    return (xcd < r ? xcd * (q + 1) : r * (q + 1) + (xcd - r) * q) + loc;
}

// ---------------- input conversion ----------------
__global__ void conv_x_kernel(const float* __restrict__ x, f16* __restrict__ A1b) {
    long idx = (long)blockIdx.x * 256 + threadIdx.x;  // m*80 + c
    if (idx >= (long)NN * 80) return;
    int m = (int)(idx / 80), c = (int)(idx % 80);
    if (c < 75) {
        float4 v = *(const float4*)(x + (long)m * F0 + 4 * c);
        f16x4 h = {(f16)v.x, (f16)v.y, (f16)v.z, (f16)v.w};
        *(f16x4*)(A1b + (long)m * KP1 + 4 * c) = h;
    } else {
        f16x4 z = {};
        *(f16x4*)(A1b + (long)m * KP1 + 300 + (c - 75) * 4) = z;
    }
}

// Wt1[n][k] (f16, [512][640]) : k<300 -> Ws1[k][n]; 300..319 -> 0;
//                               320..619 -> Wn1[k-320][n]; 620..639 -> 0
__global__ void prep_w1_kernel(const float* __restrict__ Ws1, const float* __restrict__ Wn1,
                               f16* __restrict__ Wt1) {
    int idx = blockIdx.x * 256 + threadIdx.x;
    if (idx >= F1 * KP1) return;
    int n = idx / KP1, k = idx % KP1;
    float v = 0.f;
    if (k < 300) v = Ws1[k * F1 + n];
    else if (k >= XOFF && k < XOFF + 300) v = Wn1[(k - XOFF) * F1 + n];
    Wt1[idx] = (f16)v;
}

// Wt2cat[n][k] ([512][512]) : n<256 -> Wn2[k][n] ; n>=256 -> Ws2[k][n-256]
__global__ void prep_w2cat_kernel(const float* __restrict__ Ws2, const float* __restrict__ Wn2,
                                  f16* __restrict__ Wt) {
    int idx = blockIdx.x * 256 + threadIdx.x;
    if (idx >= 2 * F2 * F1) return;
    int n = idx / F1, k = idx % F1;
    float v = (n < F2) ? Wn2[k * F2 + n] : Ws2[k * F2 + (n - F2)];
    Wt[idx] = (f16)v;
}

// ---------------- CSR build ----------------
__global__ void count_kernel(const int* __restrict__ dst, int* __restrict__ cnt) {
    int e = blockIdx.x * 256 + threadIdx.x;
    if (e < NE) atomicAdd(&cnt[dst[e]], 1);
}

__global__ __launch_bounds__(1024) void scan_kernel(const int* __restrict__ cnt,
                                                    int* __restrict__ row_ptr,
                                                    int* __restrict__ cursor) {
    constexpr int CH = (NN + 1023) / 1024;  // 20
    __shared__ int part[1024];
    const int t = threadIdx.x;
    int base = t * CH;
    int s = 0;
    #pragma unroll
    for (int i = 0; i < CH; ++i) {
        int idx = base + i;
        if (idx < NN) s += cnt[idx];
    }
    part[t] = s;
    __syncthreads();
    #pragma unroll
    for (int off = 1; off < 1024; off <<= 1) {
        int v = (t >= off) ? part[t - off] : 0;
        __syncthreads();
        part[t] += v;
        __syncthreads();
    }
    int run = (t == 0) ? 0 : part[t - 1];
    #pragma unroll
    for (int i = 0; i < CH; ++i) {
        int idx = base + i;
        if (idx < NN) {
            row_ptr[idx] = run;
            cursor[idx] = run;
            run += cnt[idx];
        }
    }
    if (t == 1023) row_ptr[NN] = part[1023];
}

__global__ void fill_kernel(const int* __restrict__ src, const int* __restrict__ dst,
                            int* __restrict__ cursor, int* __restrict__ csr_src) {
    int e = blockIdx.x * 256 + threadIdx.x;
    if (e >= NE) return;
    int pos = atomicAdd(&cursor[dst[e]], 1);
    csr_src[pos] = src[e];
}

// ---------------- XCD-pinned window gathers ----------------
// window = blockIdx & 7 (hardware round-robins blocks across XCDs): each XCD
// sees ONE window's table slice -> loaded once chip-wide, L2-resident.

// gather1: 8 windows x 40 feats over x-region cols [0,320).
// 8 lanes/node, lanes 0..4 active (5 x f16x8 = 40 feats). Grid 5000 = 8 x 625.
__global__ __launch_bounds__(256) void gather1_kernel(const int* __restrict__ row_ptr,
                                                      const int* __restrict__ csr,
                                                      f16* __restrict__ A1b) {
    int win = blockIdx.x & 7;
    int g = (blockIdx.x >> 3) * 256 + threadIdx.x;  // 0..159999
    int j = g & 7;
    if (j >= 5) return;
    int m = g >> 3;
    int off = win * 40 + j * 8;
    int beg = row_ptr[m], end = row_ptr[m + 1];
    float a[8] = {};
    for (int e = beg; e < end; ++e) {
        int s = csr[e];
        f16x8 v = *(const f16x8*)(A1b + (long)s * KP1 + off);
        #pragma unroll
        for (int k = 0; k < 8; ++k) a[k] += (float)v[k];
    }
    float inv = 1.0f / fmaxf((float)(end - beg), 1.0f);
    f16x8 w;
    #pragma unroll
    for (int k = 0; k < 8; ++k) w[k] = (f16)(a[k] * inv);
    *(f16x8*)(A1b + (long)m * KP1 + XOFF + off) = w;
}

// gather2: 8 windows x 32 feats; 4 lanes/node (4 x f16x8). Grid 2504 = 8 x 313.
// out[m][c] = mean_e(t2[src][c]) + self[m][c]
__global__ __launch_bounds__(256) void gather2_kernel(const int* __restrict__ row_ptr,
                                                      const int* __restrict__ csr,
                                                      const f16* __restrict__ t2,
                                                      const float* __restrict__ self,
                                                      float* __restrict__ out) {
    int win = blockIdx.x & 7;
    int g = (blockIdx.x >> 3) * 256 + threadIdx.x;
    int m = g >> 2;
    if (m >= NN) return;
    int off = win * 32 + (g & 3) * 8;
    int beg = row_ptr[m], end = row_ptr[m + 1];
    float a[8] = {};
    for (int e = beg; e < end; ++e) {
        int s = csr[e];
        f16x8 v = *(const f16x8*)(t2 + (long)s * F2 + off);
        #pragma unroll
        for (int k = 0; k < 8; ++k) a[k] += (float)v[k];
    }
    float inv = 1.0f / fmaxf((float)(end - beg), 1.0f);
    const float* sp = self + (long)m * F2 + off;
    f32x4 s0 = *(const f32x4*)(sp);
    f32x4 s1 = *(const f32x4*)(sp + 4);
    f32x4 w0 = {a[0]*inv + s0[0], a[1]*inv + s0[1], a[2]*inv + s0[2], a[3]*inv + s0[3]};
    f32x4 w1 = {a[4]*inv + s1[0], a[5]*inv + s1[1], a[6]*inv + s1[2], a[7]*inv + s1[3]};
    float* op = out + (long)m * F2 + off;
    *(f32x4*)(op) = w0;
    *(f32x4*)(op + 4) = w1;
}

// ---------------- f16 MFMA GEMM ----------------
// C = A[M][K] @ Bt[N][K]^T. BM=64, BN=128, BK=64; 4 waves (2x2), wave tile 32x64.
// 1D grid, n-fastest within m-panel, xcd_swz -> each XCD owns contiguous
// m-panels (A-panel fetched once chip-wide). N fixed at 512 (4 n-blocks).
// MODE 1: h1 = relu(C + bias) (f16)
// MODE 2: n<F2 -> t2[m][n] = f16(C); n>=F2 -> self[m][n-F2] = C + bias[n-F2] (f32)
template<int MODE>
__global__ __launch_bounds__(256) void hgemm_kernel(
    const f16* __restrict__ A, const f16* __restrict__ Bt,
    const float* __restrict__ bias, float* __restrict__ out_f32,
    f16* __restrict__ out_f16, int M, int N, int K, int nb)
{
    __shared__ f16 As[64][72];
    __shared__ f16 Bs[128][72];

    const int wid = xcd_swz(blockIdx.x, nb);
    const int m0 = (wid >> 2) * 64, n0 = (wid & 3) * 128;

    const int t = threadIdx.x;
    const int lane = t & 63, wave = t >> 6;
    const int wr = wave >> 1, wc = wave & 1;
    const int ar = t >> 2, ac = (t & 3) * 16;
    const int br = t >> 1, bc = (t & 1) * 32;

    f32x4 acc[2][4] = {};

    for (int k0 = 0; k0 < K; k0 += 64) {
        {
            const f16* ga = A + (long)(m0 + ar) * K + k0 + ac;
            bool mok = (m0 + ar) < M;
            f16x8 v0 = mok ? *(const f16x8*)(ga + 0) : (f16x8){};
            f16x8 v1 = mok ? *(const f16x8*)(ga + 8) : (f16x8){};
            *(f16x8*)&As[ar][ac + 0] = v0;
            *(f16x8*)&As[ar][ac + 8] = v1;
        }
        {
            const f16* gb = Bt + (long)(n0 + br) * K + k0 + bc;
            f16x8 v0 = *(const f16x8*)(gb + 0);
            f16x8 v1 = *(const f16x8*)(gb + 8);
            f16x8 v2 = *(const f16x8*)(gb + 16);
            f16x8 v3 = *(const f16x8*)(gb + 24);
            *(f16x8*)&Bs[br][bc + 0]  = v0;
            *(f16x8*)&Bs[br][bc + 8]  = v1;
            *(f16x8*)&Bs[br][bc + 16] = v2;
            *(f16x8*)&Bs[br][bc + 24] = v3;
        }
        __syncthreads();
        #pragma unroll
        for (int kk = 0; kk < 2; ++kk) {
            f16x8 af[2], bf[4];
            #pragma unroll
            for (int i = 0; i < 2; ++i)
                af[i] = *(const f16x8*)&As[wr * 32 + i * 16 + (lane & 15)][kk * 32 + (lane >> 4) * 8];
            #pragma unroll
            for (int j = 0; j < 4; ++j)
                bf[j] = *(const f16x8*)&Bs[wc * 64 + j * 16 + (lane & 15)][kk * 32 + (lane >> 4) * 8];
            #pragma unroll
            for (int i = 0; i < 2; ++i)
                #pragma unroll
                for (int j = 0; j < 4; ++j)
                    acc[i][j] = __builtin_amdgcn_mfma_f32_16x16x32_f16(af[i], bf[j], acc[i][j], 0, 0, 0);
        }
        __syncthreads();
    }

    // C/D layout: col = lane&15, row = (lane>>4)*4 + q  [m89-verified]
    const int cr = (lane >> 4) * 4, cc = lane & 15;
    #pragma unroll
    for (int i = 0; i < 2; ++i) {
        #pragma unroll
        for (int j = 0; j < 4; ++j) {
            int n = n0 + wc * 64 + j * 16 + cc;
            float b;
            if (MODE == 1) b = bias[n];
            else           b = (n >= F2) ? bias[n - F2] : 0.f;
            #pragma unroll
            for (int q = 0; q < 4; ++q) {
                int m = m0 + wr * 32 + i * 16 + cr + q;
                if (m >= M) continue;
                float v = acc[i][j][q];
                if (MODE == 1) {
                    out_f16[(long)m * N + n] = (f16)fmaxf(v + b, 0.f);
                } else {
                    if (n < F2) out_f16[(long)m * F2 + n] = (f16)v;
                    else        out_f32[(long)m * F2 + (n - F2)] = v + b;
                }
            }
        }
    }
}

extern "C" void kernel_launch(void* const* d_in, const int* in_sizes, int n_in,
                              void* d_out, int out_size, void* d_ws, size_t ws_size,
                              hipStream_t stream) {
    const float* x   = (const float*)d_in[0];
    const float* Ws1 = (const float*)d_in[1];
    const float* Wn1 = (const float*)d_in[2];
    const float* b1  = (const float*)d_in[3];
    const float* Ws2 = (const float*)d_in[4];
    const float* Wn2 = (const float*)d_in[5];
    const float* b2  = (const float*)d_in[6];
    const int* src   = (const int*)d_in[7];
    const int* dst   = (const int*)d_in[8];
    float* out = (float*)d_out;

    // workspace layout (bytes, 16B aligned):
    char* ws = (char*)d_ws;
    int* row_ptr = (int*)(ws);                      // 20001 i32   [0 .. 80,064)
    int* csr_src = (int*)(ws + 80064);              // 640000 i32  [.. 2,640,064)
    int* cursor  = (int*)(ws + 2640064);            // 20000 i32   [.. 2,720,064)
    f16* A1b     = (f16*)(ws + 2720064);            // 20000x640   [.. 28,320,064)
    f16* h1      = (f16*)(ws + 28320064);           // 20000x512   [.. 48,800,064)
    f16* t2      = (f16*)(ws + 48800064);           // 20000x256   [.. 59,040,064)
    float* selfp = (float*)(ws + 59040064);         // 20000x256 f32 [.. 79,520,064)
    f16* Wt1     = (f16*)(ws + 79520064);           // 512x640     [.. 80,175,424)
    f16* Wt2cat  = (f16*)(ws + 80175424);           // 512x512     [.. 80,699,712)

    // ---- prep: conversions + CSR build ----
    conv_x_kernel<<<(int)(((long)NN * 80) / 256), 256, 0, stream>>>(x, A1b);
    prep_w1_kernel<<<(F1 * KP1) / 256, 256, 0, stream>>>(Ws1, Wn1, Wt1);
    prep_w2cat_kernel<<<(2 * F2 * F1) / 256, 256, 0, stream>>>(Ws2, Wn2, Wt2cat);

    hipMemsetAsync(cursor, 0, NN * sizeof(int), stream);
    count_kernel<<<(NE + 255) / 256, 256, 0, stream>>>(dst, cursor);
    scan_kernel<<<1, 1024, 0, stream>>>(cursor, row_ptr, cursor);
    fill_kernel<<<(NE + 255) / 256, 256, 0, stream>>>(src, dst, cursor, csr_src);

    // ---- layer 1: XCD-pinned window gather, then concat-GEMM + relu ----
    gather1_kernel<<<8 * 625, 256, 0, stream>>>(row_ptr, csr_src, A1b);
    hgemm_kernel<1><<<313 * 4, 256, 0, stream>>>(A1b, Wt1, b1, nullptr, h1, NN, F1, KP1, 313 * 4);

    // ---- layer 2: fused [t2 | self] GEMM, then XCD-pinned gather+add ----
    hgemm_kernel<2><<<313 * 4, 256, 0, stream>>>(h1, Wt2cat, b2, selfp, t2, NN, 2 * F2, F1, 313 * 4);
    gather2_kernel<<<8 * 313, 256, 0, stream>>>(row_ptr, csr_src, t2, selfp, out);
}

// Round 11
// 371.692 us; speedup vs baseline: 1.1660x; 1.1660x over previous
//
#include <hip/hip_runtime.h>

// GraphSAGE 2-layer forward, MI355X. Round 10 (resubmit after broker timeout):
//  - gathers back to Round-8 structure (seg-major + xcd_swz, all lanes active)
//  - edge loop unrolled x4 -> 4 outstanding table loads (latency-bound fix)
//  - csr_src as uint16 (NN=20000 < 65536): halves csr traffic & L2 pollution
// A1b[20000][640] f16 = [x(300) | 0(20) | agg(300) | 0(20)]
// h1 = relu(A1b @ Wt1^T + b1) (f16)
// [t2 | self] = h1 @ [Wn2^T | Ws2^T]; out = mean_agg(t2) + self

typedef _Float16 f16;
typedef _Float16 f16x4 __attribute__((ext_vector_type(4)));
typedef _Float16 f16x8 __attribute__((ext_vector_type(8)));
typedef float f32x4 __attribute__((ext_vector_type(4)));
typedef unsigned short u16;

constexpr int NN = 20000;   // nodes
constexpr int NE = 640000;  // edges
constexpr int F0 = 300;     // in feats
constexpr int F1 = 512;     // hidden
constexpr int F2 = 256;     // classes
constexpr int KP1 = 640;    // padded concat-K for layer 1
constexpr int XOFF = 320;   // agg region start inside A1b row

// bijective XCD-contiguous swizzle (m204)
__device__ __forceinline__ int xcd_swz(int b, int nb) {
    int xcd = b & 7, loc = b >> 3;
    int q = nb >> 3, r = nb & 7;
    return (xcd < r ? xcd * (q + 1) : r * (q + 1) + (xcd - r) * q) + loc;
}

// ---------------- input conversion ----------------
__global__ void conv_x_kernel(const float* __restrict__ x, f16* __restrict__ A1b) {
    long idx = (long)blockIdx.x * 256 + threadIdx.x;  // m*80 + c
    if (idx >= (long)NN * 80) return;
    int m = (int)(idx / 80), c = (int)(idx % 80);
    if (c < 75) {
        float4 v = *(const float4*)(x + (long)m * F0 + 4 * c);
        f16x4 h = {(f16)v.x, (f16)v.y, (f16)v.z, (f16)v.w};
        *(f16x4*)(A1b + (long)m * KP1 + 4 * c) = h;
    } else {
        f16x4 z = {};
        *(f16x4*)(A1b + (long)m * KP1 + 300 + (c - 75) * 4) = z;
    }
}

// Wt1[n][k] (f16, [512][640]) : k<300 -> Ws1[k][n]; 300..319 -> 0;
//                               320..619 -> Wn1[k-320][n]; 620..639 -> 0
__global__ void prep_w1_kernel(const float* __restrict__ Ws1, const float* __restrict__ Wn1,
                               f16* __restrict__ Wt1) {
    int idx = blockIdx.x * 256 + threadIdx.x;
    if (idx >= F1 * KP1) return;
    int n = idx / KP1, k = idx % KP1;
    float v = 0.f;
    if (k < 300) v = Ws1[k * F1 + n];
    else if (k >= XOFF && k < XOFF + 300) v = Wn1[(k - XOFF) * F1 + n];
    Wt1[idx] = (f16)v;
}

// Wt2cat[n][k] ([512][512]) : n<256 -> Wn2[k][n] ; n>=256 -> Ws2[k][n-256]
__global__ void prep_w2cat_kernel(const float* __restrict__ Ws2, const float* __restrict__ Wn2,
                                  f16* __restrict__ Wt) {
    int idx = blockIdx.x * 256 + threadIdx.x;
    if (idx >= 2 * F2 * F1) return;
    int n = idx / F1, k = idx % F1;
    float v = (n < F2) ? Wn2[k * F2 + n] : Ws2[k * F2 + (n - F2)];
    Wt[idx] = (f16)v;
}

// ---------------- CSR build ----------------
__global__ void count_kernel(const int* __restrict__ dst, int* __restrict__ cnt) {
    int e = blockIdx.x * 256 + threadIdx.x;
    if (e < NE) atomicAdd(&cnt[dst[e]], 1);
}

__global__ __launch_bounds__(1024) void scan_kernel(const int* __restrict__ cnt,
                                                    int* __restrict__ row_ptr,
                                                    int* __restrict__ cursor) {
    constexpr int CH = (NN + 1023) / 1024;  // 20
    __shared__ int part[1024];
    const int t = threadIdx.x;
    int base = t * CH;
    int s = 0;
    #pragma unroll
    for (int i = 0; i < CH; ++i) {
        int idx = base + i;
        if (idx < NN) s += cnt[idx];
    }
    part[t] = s;
    __syncthreads();
    #pragma unroll
    for (int off = 1; off < 1024; off <<= 1) {
        int v = (t >= off) ? part[t - off] : 0;
        __syncthreads();
        part[t] += v;
        __syncthreads();
    }
    int run = (t == 0) ? 0 : part[t - 1];
    #pragma unroll
    for (int i = 0; i < CH; ++i) {
        int idx = base + i;
        if (idx < NN) {
            row_ptr[idx] = run;
            cursor[idx] = run;
            run += cnt[idx];
        }
    }
    if (t == 1023) row_ptr[NN] = part[1023];
}

__global__ void fill_kernel(const int* __restrict__ src, const int* __restrict__ dst,
                            int* __restrict__ cursor, u16* __restrict__ csr16) {
    int e = blockIdx.x * 256 + threadIdx.x;
    if (e >= NE) return;
    int pos = atomicAdd(&cursor[dst[e]], 1);
    csr16[pos] = (u16)src[e];
}

// ---------------- merged chunk-major gathers (XCD-swizzled, unroll x4) ----------------
// Work item g = (seg, node, lane8): seg-major; xcd_swz gives each XCD a
// contiguous g-range -> its L2 holds ~one 64-feat window (2.56MB) + 1.28MB csr.

// gather1: reads A1b cols [seg*64, seg*64+64), writes mean to cols XOFF + same
__global__ __launch_bounds__(256) void gather1_kernel(const int* __restrict__ row_ptr,
                                                      const u16* __restrict__ csr,
                                                      f16* __restrict__ A1b) {
    int wid = xcd_swz(blockIdx.x, 5 * 625);
    int seg = wid / 625;
    int g = (wid % 625) * 256 + threadIdx.x;  // 0..159999
    int m = g >> 3;
    int off = seg * 64 + (g & 7) * 8;
    int beg = row_ptr[m], end = row_ptr[m + 1];
    float a[8] = {};
    int e = beg;
    for (; e + 4 <= end; e += 4) {
        int s0 = csr[e + 0], s1 = csr[e + 1], s2 = csr[e + 2], s3 = csr[e + 3];
        f16x8 v0 = *(const f16x8*)(A1b + (long)s0 * KP1 + off);
        f16x8 v1 = *(const f16x8*)(A1b + (long)s1 * KP1 + off);
        f16x8 v2 = *(const f16x8*)(A1b + (long)s2 * KP1 + off);
        f16x8 v3 = *(const f16x8*)(A1b + (long)s3 * KP1 + off);
        #pragma unroll
        for (int j = 0; j < 8; ++j)
            a[j] += ((float)v0[j] + (float)v1[j]) + ((float)v2[j] + (float)v3[j]);
    }
    for (; e < end; ++e) {
        int s = csr[e];
        f16x8 v = *(const f16x8*)(A1b + (long)s * KP1 + off);
        #pragma unroll
        for (int j = 0; j < 8; ++j) a[j] += (float)v[j];
    }
    float inv = 1.0f / fmaxf((float)(end - beg), 1.0f);
    f16x8 w;
    #pragma unroll
    for (int j = 0; j < 8; ++j) w[j] = (f16)(a[j] * inv);
    *(f16x8*)(A1b + (long)m * KP1 + XOFF + off) = w;
}

// gather2: out[m][c] = mean_e(t2[src][c]) + self[m][c]
__global__ __launch_bounds__(256) void gather2_kernel(const int* __restrict__ row_ptr,
                                                      const u16* __restrict__ csr,
                                                      const f16* __restrict__ t2,
                                                      const float* __restrict__ self,
                                                      float* __restrict__ out) {
    int wid = xcd_swz(blockIdx.x, 4 * 625);
    int seg = wid / 625;
    int g = (wid % 625) * 256 + threadIdx.x;
    int m = g >> 3;
    int off = seg * 64 + (g & 7) * 8;
    int beg = row_ptr[m], end = row_ptr[m + 1];
    float a[8] = {};
    int e = beg;
    for (; e + 4 <= end; e += 4) {
        int s0 = csr[e + 0], s1 = csr[e + 1], s2 = csr[e + 2], s3 = csr[e + 3];
        f16x8 v0 = *(const f16x8*)(t2 + (long)s0 * F2 + off);
        f16x8 v1 = *(const f16x8*)(t2 + (long)s1 * F2 + off);
        f16x8 v2 = *(const f16x8*)(t2 + (long)s2 * F2 + off);
        f16x8 v3 = *(const f16x8*)(t2 + (long)s3 * F2 + off);
        #pragma unroll
        for (int j = 0; j < 8; ++j)
            a[j] += ((float)v0[j] + (float)v1[j]) + ((float)v2[j] + (float)v3[j]);
    }
    for (; e < end; ++e) {
        int s = csr[e];
        f16x8 v = *(const f16x8*)(t2 + (long)s * F2 + off);
        #pragma unroll
        for (int j = 0; j < 8; ++j) a[j] += (float)v[j];
    }
    float inv = 1.0f / fmaxf((float)(end - beg), 1.0f);
    const float* sp = self + (long)m * F2 + off;
    f32x4 s0 = *(const f32x4*)(sp);
    f32x4 s1 = *(const f32x4*)(sp + 4);
    f32x4 w0 = {a[0]*inv + s0[0], a[1]*inv + s0[1], a[2]*inv + s0[2], a[3]*inv + s0[3]};
    f32x4 w1 = {a[4]*inv + s1[0], a[5]*inv + s1[1], a[6]*inv + s1[2], a[7]*inv + s1[3]};
    float* op = out + (long)m * F2 + off;
    *(f32x4*)(op) = w0;
    *(f32x4*)(op + 4) = w1;
}

// ---------------- f16 MFMA GEMM ----------------
// C = A[M][K] @ Bt[N][K]^T. BM=64, BN=128, BK=64; 4 waves (2x2), wave tile 32x64.
// MODE 1: h1 = relu(C + bias) (f16)
// MODE 2: n<F2 -> t2[m][n] = f16(C); n>=F2 -> self[m][n-F2] = C + bias[n-F2] (f32)
template<int MODE>
__global__ __launch_bounds__(256) void hgemm_kernel(
    const f16* __restrict__ A, const f16* __restrict__ Bt,
    const float* __restrict__ bias, float* __restrict__ out_f32,
    f16* __restrict__ out_f16, int M, int N, int K)
{
    __shared__ f16 As[64][72];
    __shared__ f16 Bs[128][72];

    const int t = threadIdx.x;
    const int lane = t & 63, wave = t >> 6;
    const int wr = wave >> 1, wc = wave & 1;
    const int m0 = blockIdx.x * 64, n0 = blockIdx.y * 128;
    const int ar = t >> 2, ac = (t & 3) * 16;
    const int br = t >> 1, bc = (t & 1) * 32;

    f32x4 acc[2][4] = {};

    for (int k0 = 0; k0 < K; k0 += 64) {
        {
            const f16* ga = A + (long)(m0 + ar) * K + k0 + ac;
            bool mok = (m0 + ar) < M;
            f16x8 v0 = mok ? *(const f16x8*)(ga + 0) : (f16x8){};
            f16x8 v1 = mok ? *(const f16x8*)(ga + 8) : (f16x8){};
            *(f16x8*)&As[ar][ac + 0] = v0;
            *(f16x8*)&As[ar][ac + 8] = v1;
        }
        {
            const f16* gb = Bt + (long)(n0 + br) * K + k0 + bc;
            f16x8 v0 = *(const f16x8*)(gb + 0);
            f16x8 v1 = *(const f16x8*)(gb + 8);
            f16x8 v2 = *(const f16x8*)(gb + 16);
            f16x8 v3 = *(const f16x8*)(gb + 24);
            *(f16x8*)&Bs[br][bc + 0]  = v0;
            *(f16x8*)&Bs[br][bc + 8]  = v1;
            *(f16x8*)&Bs[br][bc + 16] = v2;
            *(f16x8*)&Bs[br][bc + 24] = v3;
        }
        __syncthreads();
        #pragma unroll
        for (int kk = 0; kk < 2; ++kk) {
            f16x8 af[2], bf[4];
            #pragma unroll
            for (int i = 0; i < 2; ++i)
                af[i] = *(const f16x8*)&As[wr * 32 + i * 16 + (lane & 15)][kk * 32 + (lane >> 4) * 8];
            #pragma unroll
            for (int j = 0; j < 4; ++j)
                bf[j] = *(const f16x8*)&Bs[wc * 64 + j * 16 + (lane & 15)][kk * 32 + (lane >> 4) * 8];
            #pragma unroll
            for (int i = 0; i < 2; ++i)
                #pragma unroll
                for (int j = 0; j < 4; ++j)
                    acc[i][j] = __builtin_amdgcn_mfma_f32_16x16x32_f16(af[i], bf[j], acc[i][j], 0, 0, 0);
        }
        __syncthreads();
    }

    // C/D layout: col = lane&15, row = (lane>>4)*4 + q  [m89-verified]
    const int cr = (lane >> 4) * 4, cc = lane & 15;
    #pragma unroll
    for (int i = 0; i < 2; ++i) {
        #pragma unroll
        for (int j = 0; j < 4; ++j) {
            int n = n0 + wc * 64 + j * 16 + cc;
            float b;
            if (MODE == 1) b = bias[n];
            else           b = (n >= F2) ? bias[n - F2] : 0.f;
            #pragma unroll
            for (int q = 0; q < 4; ++q) {
                int m = m0 + wr * 32 + i * 16 + cr + q;
                if (m >= M) continue;
                float v = acc[i][j][q];
                if (MODE == 1) {
                    out_f16[(long)m * N + n] = (f16)fmaxf(v + b, 0.f);
                } else {
                    if (n < F2) out_f16[(long)m * F2 + n] = (f16)v;
                    else        out_f32[(long)m * F2 + (n - F2)] = v + b;
                }
            }
        }
    }
}

extern "C" void kernel_launch(void* const* d_in, const int* in_sizes, int n_in,
                              void* d_out, int out_size, void* d_ws, size_t ws_size,
                              hipStream_t stream) {
    const float* x   = (const float*)d_in[0];
    const float* Ws1 = (const float*)d_in[1];
    const float* Wn1 = (const float*)d_in[2];
    const float* b1  = (const float*)d_in[3];
    const float* Ws2 = (const float*)d_in[4];
    const float* Wn2 = (const float*)d_in[5];
    const float* b2  = (const float*)d_in[6];
    const int* src   = (const int*)d_in[7];
    const int* dst   = (const int*)d_in[8];
    float* out = (float*)d_out;

    // workspace layout (bytes, 16B aligned):
    char* ws = (char*)d_ws;
    int* row_ptr = (int*)(ws);                      // 20001 i32   [0 .. 80,064)
    u16* csr16   = (u16*)(ws + 80064);              // 640000 u16  [.. 1,360,064)
    int* cursor  = (int*)(ws + 1360064);            // 20000 i32   [.. 1,440,064)
    f16* A1b     = (f16*)(ws + 1440064);            // 20000x640   [.. 27,040,064)
    f16* h1      = (f16*)(ws + 27040064);           // 20000x512   [.. 47,520,064)
    f16* t2      = (f16*)(ws + 47520064);           // 20000x256   [.. 57,760,064)
    float* selfp = (float*)(ws + 57760064);         // 20000x256 f32 [.. 78,240,064)
    f16* Wt1     = (f16*)(ws + 78240064);           // 512x640     [.. 78,895,424)
    f16* Wt2cat  = (f16*)(ws + 78895424);           // 512x512     [.. 79,419,712)

    // ---- prep: conversions + CSR build ----
    conv_x_kernel<<<(int)(((long)NN * 80) / 256), 256, 0, stream>>>(x, A1b);
    prep_w1_kernel<<<(F1 * KP1) / 256, 256, 0, stream>>>(Ws1, Wn1, Wt1);
    prep_w2cat_kernel<<<(2 * F2 * F1) / 256, 256, 0, stream>>>(Ws2, Wn2, Wt2cat);

    hipMemsetAsync(cursor, 0, NN * sizeof(int), stream);
    count_kernel<<<(NE + 255) / 256, 256, 0, stream>>>(dst, cursor);
    scan_kernel<<<1, 1024, 0, stream>>>(cursor, row_ptr, cursor);
    fill_kernel<<<(NE + 255) / 256, 256, 0, stream>>>(src, dst, cursor, csr16);

    // ---- layer 1: merged gather (XCD-swizzled), concat-GEMM + relu ----
    gather1_kernel<<<5 * 625, 256, 0, stream>>>(row_ptr, csr16, A1b);
    dim3 g1((NN + 63) / 64, F1 / 128);
    hgemm_kernel<1><<<g1, 256, 0, stream>>>(A1b, Wt1, b1, nullptr, h1, NN, F1, KP1);

    // ---- layer 2: fused [t2 | self] GEMM, then merged gather+add ----
    dim3 g2((NN + 63) / 64, (2 * F2) / 128);
    hgemm_kernel<2><<<g2, 256, 0, stream>>>(h1, Wt2cat, b2, selfp, t2, NN, 2 * F2, F1);
    gather2_kernel<<<4 * 625, 256, 0, stream>>>(row_ptr, csr16, t2, selfp, out);
}

// Round 13
// 361.656 us; speedup vs baseline: 1.1984x; 1.0278x over previous
//
#include <hip/hip_runtime.h>

// GraphSAGE 2-layer forward, MI355X. Round 12 (resubmit after broker timeout):
//  - gathers: unroll x8 (8 outstanding table loads) + packed-f16 accumulation
//    (v_pk_add_f16, 4 VALU/edge instead of 16)
//  - prep fusion: conv_x + w1 + w2cat + degree-count in ONE dispatch
// A1b[20000][640] f16 = [x(300) | 0(20) | agg(300) | 0(20)]
// h1 = relu(A1b @ Wt1^T + b1) (f16)
// [t2 | self] = h1 @ [Wn2^T | Ws2^T]; out = mean_agg(t2) + self

typedef _Float16 f16;
typedef _Float16 f16x4 __attribute__((ext_vector_type(4)));
typedef _Float16 f16x8 __attribute__((ext_vector_type(8)));
typedef float f32x4 __attribute__((ext_vector_type(4)));
typedef unsigned short u16;

constexpr int NN = 20000;   // nodes
constexpr int NE = 640000;  // edges
constexpr int F0 = 300;     // in feats
constexpr int F1 = 512;     // hidden
constexpr int F2 = 256;     // classes
constexpr int KP1 = 640;    // padded concat-K for layer 1
constexpr int XOFF = 320;   // agg region start inside A1b row

// bijective XCD-contiguous swizzle (m204)
__device__ __forceinline__ int xcd_swz(int b, int nb) {
    int xcd = b & 7, loc = b >> 3;
    int q = nb >> 3, r = nb & 7;
    return (xcd < r ? xcd * (q + 1) : r * (q + 1) + (xcd - r) * q) + loc;
}

// ---------------- fused prep: conv_x | Wt1 | Wt2cat | degree count ----------------
// block ranges: [0,6250) conv_x, [6250,7530) w1, [7530,8554) w2cat, [8554,11054) count
__global__ __launch_bounds__(256) void prep_all_kernel(
    const float* __restrict__ x, const float* __restrict__ Ws1,
    const float* __restrict__ Wn1, const float* __restrict__ Ws2,
    const float* __restrict__ Wn2, const int* __restrict__ dst,
    f16* __restrict__ A1b, f16* __restrict__ Wt1, f16* __restrict__ Wt2cat,
    int* __restrict__ cnt)
{
    int b = blockIdx.x, t = threadIdx.x;
    if (b < 6250) {
        // conv_x: x f32 -> A1b cols 0..299 (f16); zero cols 300..319
        long idx = (long)b * 256 + t;  // m*80 + c
        int m = (int)(idx / 80), c = (int)(idx % 80);
        if (c < 75) {
            float4 v = *(const float4*)(x + (long)m * F0 + 4 * c);
            f16x4 h = {(f16)v.x, (f16)v.y, (f16)v.z, (f16)v.w};
            *(f16x4*)(A1b + (long)m * KP1 + 4 * c) = h;
        } else {
            f16x4 z = {};
            *(f16x4*)(A1b + (long)m * KP1 + 300 + (c - 75) * 4) = z;
        }
    } else if (b < 7530) {
        // Wt1[n][k]: k<300 -> Ws1[k][n]; 300..319 -> 0; 320..619 -> Wn1[k-320][n]; else 0
        int idx = (b - 6250) * 256 + t;
        int n = idx / KP1, k = idx % KP1;
        float v = 0.f;
        if (k < 300) v = Ws1[k * F1 + n];
        else if (k >= XOFF && k < XOFF + 300) v = Wn1[(k - XOFF) * F1 + n];
        Wt1[idx] = (f16)v;
    } else if (b < 8554) {
        // Wt2cat[n][k]: n<256 -> Wn2[k][n]; n>=256 -> Ws2[k][n-256]
        int idx = (b - 7530) * 256 + t;
        int n = idx / F1, k = idx % F1;
        float v = (n < F2) ? Wn2[k * F2 + n] : Ws2[k * F2 + (n - F2)];
        Wt2cat[idx] = (f16)v;
    } else {
        // degree count
        int e = (b - 8554) * 256 + t;
        if (e < NE) atomicAdd(&cnt[dst[e]], 1);
    }
}

// ---------------- CSR build ----------------
__global__ __launch_bounds__(1024) void scan_kernel(const int* __restrict__ cnt,
                                                    int* __restrict__ row_ptr,
                                                    int* __restrict__ cursor) {
    constexpr int CH = (NN + 1023) / 1024;  // 20
    __shared__ int part[1024];
    const int t = threadIdx.x;
    int base = t * CH;
    int s = 0;
    #pragma unroll
    for (int i = 0; i < CH; ++i) {
        int idx = base + i;
        if (idx < NN) s += cnt[idx];
    }
    part[t] = s;
    __syncthreads();
    #pragma unroll
    for (int off = 1; off < 1024; off <<= 1) {
        int v = (t >= off) ? part[t - off] : 0;
        __syncthreads();
        part[t] += v;
        __syncthreads();
    }
    int run = (t == 0) ? 0 : part[t - 1];
    #pragma unroll
    for (int i = 0; i < CH; ++i) {
        int idx = base + i;
        if (idx < NN) {
            row_ptr[idx] = run;
            cursor[idx] = run;
            run += cnt[idx];
        }
    }
    if (t == 1023) row_ptr[NN] = part[1023];
}

__global__ void fill_kernel(const int* __restrict__ src, const int* __restrict__ dst,
                            int* __restrict__ cursor, u16* __restrict__ csr16) {
    int e = blockIdx.x * 256 + threadIdx.x;
    if (e >= NE) return;
    int pos = atomicAdd(&cursor[dst[e]], 1);
    csr16[pos] = (u16)src[e];
}

// ---------------- merged chunk-major gathers (XCD-swizzled, unroll x8, pk-f16) ----------------
// Work item g = (seg, node, lane8): seg-major; xcd_swz gives each XCD a
// contiguous g-range -> its L2 holds ~one 64-feat window (2.56MB) + 1.28MB csr.

// gather1: reads A1b cols [seg*64, seg*64+64), writes mean to cols XOFF + same
__global__ __launch_bounds__(256) void gather1_kernel(const int* __restrict__ row_ptr,
                                                      const u16* __restrict__ csr,
                                                      f16* __restrict__ A1b) {
    int wid = xcd_swz(blockIdx.x, 5 * 625);
    int seg = wid / 625;
    int g = (wid % 625) * 256 + threadIdx.x;  // 0..159999
    int m = g >> 3;
    int off = seg * 64 + (g & 7) * 8;
    int beg = row_ptr[m], end = row_ptr[m + 1];
    f16x8 acc = {};
    int e = beg;
    for (; e + 8 <= end; e += 8) {
        int s0 = csr[e + 0], s1 = csr[e + 1], s2 = csr[e + 2], s3 = csr[e + 3];
        int s4 = csr[e + 4], s5 = csr[e + 5], s6 = csr[e + 6], s7 = csr[e + 7];
        f16x8 v0 = *(const f16x8*)(A1b + (long)s0 * KP1 + off);
        f16x8 v1 = *(const f16x8*)(A1b + (long)s1 * KP1 + off);
        f16x8 v2 = *(const f16x8*)(A1b + (long)s2 * KP1 + off);
        f16x8 v3 = *(const f16x8*)(A1b + (long)s3 * KP1 + off);
        f16x8 v4 = *(const f16x8*)(A1b + (long)s4 * KP1 + off);
        f16x8 v5 = *(const f16x8*)(A1b + (long)s5 * KP1 + off);
        f16x8 v6 = *(const f16x8*)(A1b + (long)s6 * KP1 + off);
        f16x8 v7 = *(const f16x8*)(A1b + (long)s7 * KP1 + off);
        acc += ((v0 + v1) + (v2 + v3)) + ((v4 + v5) + (v6 + v7));
    }
    for (; e < end; ++e) {
        int s = csr[e];
        acc += *(const f16x8*)(A1b + (long)s * KP1 + off);
    }
    float inv = 1.0f / fmaxf((float)(end - beg), 1.0f);
    f16x8 w;
    #pragma unroll
    for (int j = 0; j < 8; ++j) w[j] = (f16)((float)acc[j] * inv);
    *(f16x8*)(A1b + (long)m * KP1 + XOFF + off) = w;
}

// gather2: out[m][c] = mean_e(t2[src][c]) + self[m][c]
__global__ __launch_bounds__(256) void gather2_kernel(const int* __restrict__ row_ptr,
                                                      const u16* __restrict__ csr,
                                                      const f16* __restrict__ t2,
                                                      const float* __restrict__ self,
                                                      float* __restrict__ out) {
    int wid = xcd_swz(blockIdx.x, 4 * 625);
    int seg = wid / 625;
    int g = (wid % 625) * 256 + threadIdx.x;
    int m = g >> 3;
    int off = seg * 64 + (g & 7) * 8;
    int beg = row_ptr[m], end = row_ptr[m + 1];
    f16x8 acc = {};
    int e = beg;
    for (; e + 8 <= end; e += 8) {
        int s0 = csr[e + 0], s1 = csr[e + 1], s2 = csr[e + 2], s3 = csr[e + 3];
        int s4 = csr[e + 4], s5 = csr[e + 5], s6 = csr[e + 6], s7 = csr[e + 7];
        f16x8 v0 = *(const f16x8*)(t2 + (long)s0 * F2 + off);
        f16x8 v1 = *(const f16x8*)(t2 + (long)s1 * F2 + off);
        f16x8 v2 = *(const f16x8*)(t2 + (long)s2 * F2 + off);
        f16x8 v3 = *(const f16x8*)(t2 + (long)s3 * F2 + off);
        f16x8 v4 = *(const f16x8*)(t2 + (long)s4 * F2 + off);
        f16x8 v5 = *(const f16x8*)(t2 + (long)s5 * F2 + off);
        f16x8 v6 = *(const f16x8*)(t2 + (long)s6 * F2 + off);
        f16x8 v7 = *(const f16x8*)(t2 + (long)s7 * F2 + off);
        acc += ((v0 + v1) + (v2 + v3)) + ((v4 + v5) + (v6 + v7));
    }
    for (; e < end; ++e) {
        int s = csr[e];
        acc += *(const f16x8*)(t2 + (long)s * F2 + off);
    }
    float inv = 1.0f / fmaxf((float)(end - beg), 1.0f);
    const float* sp = self + (long)m * F2 + off;
    f32x4 s0 = *(const f32x4*)(sp);
    f32x4 s1 = *(const f32x4*)(sp + 4);
    f32x4 w0 = {(float)acc[0]*inv + s0[0], (float)acc[1]*inv + s0[1],
                (float)acc[2]*inv + s0[2], (float)acc[3]*inv + s0[3]};
    f32x4 w1 = {(float)acc[4]*inv + s1[0], (float)acc[5]*inv + s1[1],
                (float)acc[6]*inv + s1[2], (float)acc[7]*inv + s1[3]};
    float* op = out + (long)m * F2 + off;
    *(f32x4*)(op) = w0;
    *(f32x4*)(op + 4) = w1;
}

// ---------------- f16 MFMA GEMM ----------------
// C = A[M][K] @ Bt[N][K]^T. BM=64, BN=128, BK=64; 4 waves (2x2), wave tile 32x64.
// MODE 1: h1 = relu(C + bias) (f16)
// MODE 2: n<F2 -> t2[m][n] = f16(C); n>=F2 -> self[m][n-F2] = C + bias[n-F2] (f32)
template<int MODE>
__global__ __launch_bounds__(256) void hgemm_kernel(
    const f16* __restrict__ A, const f16* __restrict__ Bt,
    const float* __restrict__ bias, float* __restrict__ out_f32,
    f16* __restrict__ out_f16, int M, int N, int K)
{
    __shared__ f16 As[64][72];
    __shared__ f16 Bs[128][72];

    const int t = threadIdx.x;
    const int lane = t & 63, wave = t >> 6;
    const int wr = wave >> 1, wc = wave & 1;
    const int m0 = blockIdx.x * 64, n0 = blockIdx.y * 128;
    const int ar = t >> 2, ac = (t & 3) * 16;
    const int br = t >> 1, bc = (t & 1) * 32;

    f32x4 acc[2][4] = {};

    for (int k0 = 0; k0 < K; k0 += 64) {
        {
            const f16* ga = A + (long)(m0 + ar) * K + k0 + ac;
            bool mok = (m0 + ar) < M;
            f16x8 v0 = mok ? *(const f16x8*)(ga + 0) : (f16x8){};
            f16x8 v1 = mok ? *(const f16x8*)(ga + 8) : (f16x8){};
            *(f16x8*)&As[ar][ac + 0] = v0;
            *(f16x8*)&As[ar][ac + 8] = v1;
        }
        {
            const f16* gb = Bt + (long)(n0 + br) * K + k0 + bc;
            f16x8 v0 = *(const f16x8*)(gb + 0);
            f16x8 v1 = *(const f16x8*)(gb + 8);
            f16x8 v2 = *(const f16x8*)(gb + 16);
            f16x8 v3 = *(const f16x8*)(gb + 24);
            *(f16x8*)&Bs[br][bc + 0]  = v0;
            *(f16x8*)&Bs[br][bc + 8]  = v1;
            *(f16x8*)&Bs[br][bc + 16] = v2;
            *(f16x8*)&Bs[br][bc + 24] = v3;
        }
        __syncthreads();
        #pragma unroll
        for (int kk = 0; kk < 2; ++kk) {
            f16x8 af[2], bf[4];
            #pragma unroll
            for (int i = 0; i < 2; ++i)
                af[i] = *(const f16x8*)&As[wr * 32 + i * 16 + (lane & 15)][kk * 32 + (lane >> 4) * 8];
            #pragma unroll
            for (int j = 0; j < 4; ++j)
                bf[j] = *(const f16x8*)&Bs[wc * 64 + j * 16 + (lane & 15)][kk * 32 + (lane >> 4) * 8];
            #pragma unroll
            for (int i = 0; i < 2; ++i)
                #pragma unroll
                for (int j = 0; j < 4; ++j)
                    acc[i][j] = __builtin_amdgcn_mfma_f32_16x16x32_f16(af[i], bf[j], acc[i][j], 0, 0, 0);
        }
        __syncthreads();
    }

    // C/D layout: col = lane&15, row = (lane>>4)*4 + q  [m89-verified]
    const int cr = (lane >> 4) * 4, cc = lane & 15;
    #pragma unroll
    for (int i = 0; i < 2; ++i) {
        #pragma unroll
        for (int j = 0; j < 4; ++j) {
            int n = n0 + wc * 64 + j * 16 + cc;
            float b;
            if (MODE == 1) b = bias[n];
            else           b = (n >= F2) ? bias[n - F2] : 0.f;
            #pragma unroll
            for (int q = 0; q < 4; ++q) {
                int m = m0 + wr * 32 + i * 16 + cr + q;
                if (m >= M) continue;
                float v = acc[i][j][q];
                if (MODE == 1) {
                    out_f16[(long)m * N + n] = (f16)fmaxf(v + b, 0.f);
                } else {
                    if (n < F2) out_f16[(long)m * F2 + n] = (f16)v;
                    else        out_f32[(long)m * F2 + (n - F2)] = v + b;
                }
            }
        }
    }
}

extern "C" void kernel_launch(void* const* d_in, const int* in_sizes, int n_in,
                              void* d_out, int out_size, void* d_ws, size_t ws_size,
                              hipStream_t stream) {
    const float* x   = (const float*)d_in[0];
    const float* Ws1 = (const float*)d_in[1];
    const float* Wn1 = (const float*)d_in[2];
    const float* b1  = (const float*)d_in[3];
    const float* Ws2 = (const float*)d_in[4];
    const float* Wn2 = (const float*)d_in[5];
    const float* b2  = (const float*)d_in[6];
    const int* src   = (const int*)d_in[7];
    const int* dst   = (const int*)d_in[8];
    float* out = (float*)d_out;

    // workspace layout (bytes, 16B aligned):
    char* ws = (char*)d_ws;
    int* row_ptr = (int*)(ws);                      // 20001 i32   [0 .. 80,064)
    u16* csr16   = (u16*)(ws + 80064);              // 640000 u16  [.. 1,360,064)
    int* cursor  = (int*)(ws + 1360064);            // 20000 i32   [.. 1,440,064)
    f16* A1b     = (f16*)(ws + 1440064);            // 20000x640   [.. 27,040,064)
    f16* h1      = (f16*)(ws + 27040064);           // 20000x512   [.. 47,520,064)
    f16* t2      = (f16*)(ws + 47520064);           // 20000x256   [.. 57,760,064)
    float* selfp = (float*)(ws + 57760064);         // 20000x256 f32 [.. 78,240,064)
    f16* Wt1     = (f16*)(ws + 78240064);           // 512x640     [.. 78,895,424)
    f16* Wt2cat  = (f16*)(ws + 78895424);           // 512x512     [.. 79,419,712)

    // ---- fused prep (conv_x | Wt1 | Wt2cat | count) + CSR build ----
    hipMemsetAsync(cursor, 0, NN * sizeof(int), stream);
    prep_all_kernel<<<11054, 256, 0, stream>>>(x, Ws1, Wn1, Ws2, Wn2, dst,
                                               A1b, Wt1, Wt2cat, cursor);
    scan_kernel<<<1, 1024, 0, stream>>>(cursor, row_ptr, cursor);
    fill_kernel<<<(NE + 255) / 256, 256, 0, stream>>>(src, dst, cursor, csr16);

    // ---- layer 1: merged gather (XCD-swizzled), concat-GEMM + relu ----
    gather1_kernel<<<5 * 625, 256, 0, stream>>>(row_ptr, csr16, A1b);
    dim3 g1((NN + 63) / 64, F1 / 128);
    hgemm_kernel<1><<<g1, 256, 0, stream>>>(A1b, Wt1, b1, nullptr, h1, NN, F1, KP1);

    // ---- layer 2: fused [t2 | self] GEMM, then merged gather+add ----
    dim3 g2((NN + 63) / 64, (2 * F2) / 128);
    hgemm_kernel<2><<<g2, 256, 0, stream>>>(h1, Wt2cat, b2, selfp, t2, NN, 2 * F2, F1);
    gather2_kernel<<<4 * 625, 256, 0, stream>>>(row_ptr, csr16, t2, selfp, out);
}

// Round 15
// 347.744 us; speedup vs baseline: 1.2463x; 1.0400x over previous
//
#include <hip/hip_runtime.h>

// GraphSAGE 2-layer forward, MI355X. Round 14 (resubmit after broker timeout):
//  - gathers: 32-feat windows (10x313 / 8x313 blocks, 4 lanes/node, 16B/lane)
//    -> per-XCD working set ~2.6MB << 4MiB L2 (was ~4+MB, thrashing).
//    Same unroll x8 + pk-f16 accumulation; table bytes unchanged, csr re-read
//    doubles (L2-resident, cheap).
//  - everything else unchanged from Round 12/13.
// A1b[20000][640] f16 = [x(300) | 0(20) | agg(300) | 0(20)]
// h1 = relu(A1b @ Wt1^T + b1) (f16)
// [t2 | self] = h1 @ [Wn2^T | Ws2^T]; out = mean_agg(t2) + self

typedef _Float16 f16;
typedef _Float16 f16x4 __attribute__((ext_vector_type(4)));
typedef _Float16 f16x8 __attribute__((ext_vector_type(8)));
typedef float f32x4 __attribute__((ext_vector_type(4)));
typedef unsigned short u16;

constexpr int NN = 20000;   // nodes
constexpr int NE = 640000;  // edges
constexpr int F0 = 300;     // in feats
constexpr int F1 = 512;     // hidden
constexpr int F2 = 256;     // classes
constexpr int KP1 = 640;    // padded concat-K for layer 1
constexpr int XOFF = 320;   // agg region start inside A1b row

// bijective XCD-contiguous swizzle (m204)
__device__ __forceinline__ int xcd_swz(int b, int nb) {
    int xcd = b & 7, loc = b >> 3;
    int q = nb >> 3, r = nb & 7;
    return (xcd < r ? xcd * (q + 1) : r * (q + 1) + (xcd - r) * q) + loc;
}

// ---------------- fused prep: conv_x | Wt1 | Wt2cat | degree count ----------------
// block ranges: [0,6250) conv_x, [6250,7530) w1, [7530,8554) w2cat, [8554,11054) count
__global__ __launch_bounds__(256) void prep_all_kernel(
    const float* __restrict__ x, const float* __restrict__ Ws1,
    const float* __restrict__ Wn1, const float* __restrict__ Ws2,
    const float* __restrict__ Wn2, const int* __restrict__ dst,
    f16* __restrict__ A1b, f16* __restrict__ Wt1, f16* __restrict__ Wt2cat,
    int* __restrict__ cnt)
{
    int b = blockIdx.x, t = threadIdx.x;
    if (b < 6250) {
        // conv_x: x f32 -> A1b cols 0..299 (f16); zero cols 300..319
        long idx = (long)b * 256 + t;  // m*80 + c
        int m = (int)(idx / 80), c = (int)(idx % 80);
        if (c < 75) {
            float4 v = *(const float4*)(x + (long)m * F0 + 4 * c);
            f16x4 h = {(f16)v.x, (f16)v.y, (f16)v.z, (f16)v.w};
            *(f16x4*)(A1b + (long)m * KP1 + 4 * c) = h;
        } else {
            f16x4 z = {};
            *(f16x4*)(A1b + (long)m * KP1 + 300 + (c - 75) * 4) = z;
        }
    } else if (b < 7530) {
        // Wt1[n][k]: k<300 -> Ws1[k][n]; 300..319 -> 0; 320..619 -> Wn1[k-320][n]; else 0
        int idx = (b - 6250) * 256 + t;
        int n = idx / KP1, k = idx % KP1;
        float v = 0.f;
        if (k < 300) v = Ws1[k * F1 + n];
        else if (k >= XOFF && k < XOFF + 300) v = Wn1[(k - XOFF) * F1 + n];
        Wt1[idx] = (f16)v;
    } else if (b < 8554) {
        // Wt2cat[n][k]: n<256 -> Wn2[k][n]; n>=256 -> Ws2[k][n-256]
        int idx = (b - 7530) * 256 + t;
        int n = idx / F1, k = idx % F1;
        float v = (n < F2) ? Wn2[k * F2 + n] : Ws2[k * F2 + (n - F2)];
        Wt2cat[idx] = (f16)v;
    } else {
        // degree count
        int e = (b - 8554) * 256 + t;
        if (e < NE) atomicAdd(&cnt[dst[e]], 1);
    }
}

// ---------------- CSR build ----------------
__global__ __launch_bounds__(1024) void scan_kernel(const int* __restrict__ cnt,
                                                    int* __restrict__ row_ptr,
                                                    int* __restrict__ cursor) {
    constexpr int CH = (NN + 1023) / 1024;  // 20
    __shared__ int part[1024];
    const int t = threadIdx.x;
    int base = t * CH;
    int s = 0;
    #pragma unroll
    for (int i = 0; i < CH; ++i) {
        int idx = base + i;
        if (idx < NN) s += cnt[idx];
    }
    part[t] = s;
    __syncthreads();
    #pragma unroll
    for (int off = 1; off < 1024; off <<= 1) {
        int v = (t >= off) ? part[t - off] : 0;
        __syncthreads();
        part[t] += v;
        __syncthreads();
    }
    int run = (t == 0) ? 0 : part[t - 1];
    #pragma unroll
    for (int i = 0; i < CH; ++i) {
        int idx = base + i;
        if (idx < NN) {
            row_ptr[idx] = run;
            cursor[idx] = run;
            run += cnt[idx];
        }
    }
    if (t == 1023) row_ptr[NN] = part[1023];
}

__global__ void fill_kernel(const int* __restrict__ src, const int* __restrict__ dst,
                            int* __restrict__ cursor, u16* __restrict__ csr16) {
    int e = blockIdx.x * 256 + threadIdx.x;
    if (e >= NE) return;
    int pos = atomicAdd(&cursor[dst[e]], 1);
    csr16[pos] = (u16)src[e];
}

// ---------------- merged chunk-major gathers (32-feat windows, XCD-swizzled) ----------------
// Work item g = (seg, node, lane4): seg-major; 4 lanes/node, f16x8 (16B) per lane.
// Window slice = 20000 x 64B = 1.28MB; + csr 1.28MB -> per-XCD set ~2.6MB < 4MiB L2.

// gather1: reads A1b cols [seg*32, seg*32+32), writes mean to cols XOFF + same
__global__ __launch_bounds__(256) void gather1_kernel(const int* __restrict__ row_ptr,
                                                      const u16* __restrict__ csr,
                                                      f16* __restrict__ A1b) {
    int wid = xcd_swz(blockIdx.x, 10 * 313);
    int seg = wid / 313;
    int g = (wid % 313) * 256 + threadIdx.x;  // 0..80127
    int m = g >> 2;
    if (m >= NN) return;
    int off = seg * 32 + (g & 3) * 8;
    int beg = row_ptr[m], end = row_ptr[m + 1];
    f16x8 acc = {};
    int e = beg;
    for (; e + 8 <= end; e += 8) {
        int s0 = csr[e + 0], s1 = csr[e + 1], s2 = csr[e + 2], s3 = csr[e + 3];
        int s4 = csr[e + 4], s5 = csr[e + 5], s6 = csr[e + 6], s7 = csr[e + 7];
        f16x8 v0 = *(const f16x8*)(A1b + (long)s0 * KP1 + off);
        f16x8 v1 = *(const f16x8*)(A1b + (long)s1 * KP1 + off);
        f16x8 v2 = *(const f16x8*)(A1b + (long)s2 * KP1 + off);
        f16x8 v3 = *(const f16x8*)(A1b + (long)s3 * KP1 + off);
        f16x8 v4 = *(const f16x8*)(A1b + (long)s4 * KP1 + off);
        f16x8 v5 = *(const f16x8*)(A1b + (long)s5 * KP1 + off);
        f16x8 v6 = *(const f16x8*)(A1b + (long)s6 * KP1 + off);
        f16x8 v7 = *(const f16x8*)(A1b + (long)s7 * KP1 + off);
        acc += ((v0 + v1) + (v2 + v3)) + ((v4 + v5) + (v6 + v7));
    }
    for (; e < end; ++e) {
        int s = csr[e];
        acc += *(const f16x8*)(A1b + (long)s * KP1 + off);
    }
    float inv = 1.0f / fmaxf((float)(end - beg), 1.0f);
    f16x8 w;
    #pragma unroll
    for (int j = 0; j < 8; ++j) w[j] = (f16)((float)acc[j] * inv);
    *(f16x8*)(A1b + (long)m * KP1 + XOFF + off) = w;
}

// gather2: out[m][c] = mean_e(t2[src][c]) + self[m][c]
__global__ __launch_bounds__(256) void gather2_kernel(const int* __restrict__ row_ptr,
                                                      const u16* __restrict__ csr,
                                                      const f16* __restrict__ t2,
                                                      const float* __restrict__ self,
                                                      float* __restrict__ out) {
    int wid = xcd_swz(blockIdx.x, 8 * 313);
    int seg = wid / 313;
    int g = (wid % 313) * 256 + threadIdx.x;
    int m = g >> 2;
    if (m >= NN) return;
    int off = seg * 32 + (g & 3) * 8;
    int beg = row_ptr[m], end = row_ptr[m + 1];
    f16x8 acc = {};
    int e = beg;
    for (; e + 8 <= end; e += 8) {
        int s0 = csr[e + 0], s1 = csr[e + 1], s2 = csr[e + 2], s3 = csr[e + 3];
        int s4 = csr[e + 4], s5 = csr[e + 5], s6 = csr[e + 6], s7 = csr[e + 7];
        f16x8 v0 = *(const f16x8*)(t2 + (long)s0 * F2 + off);
        f16x8 v1 = *(const f16x8*)(t2 + (long)s1 * F2 + off);
        f16x8 v2 = *(const f16x8*)(t2 + (long)s2 * F2 + off);
        f16x8 v3 = *(const f16x8*)(t2 + (long)s3 * F2 + off);
        f16x8 v4 = *(const f16x8*)(t2 + (long)s4 * F2 + off);
        f16x8 v5 = *(const f16x8*)(t2 + (long)s5 * F2 + off);
        f16x8 v6 = *(const f16x8*)(t2 + (long)s6 * F2 + off);
        f16x8 v7 = *(const f16x8*)(t2 + (long)s7 * F2 + off);
        acc += ((v0 + v1) + (v2 + v3)) + ((v4 + v5) + (v6 + v7));
    }
    for (; e < end; ++e) {
        int s = csr[e];
        acc += *(const f16x8*)(t2 + (long)s * F2 + off);
    }
    float inv = 1.0f / fmaxf((float)(end - beg), 1.0f);
    const float* sp = self + (long)m * F2 + off;
    f32x4 s0 = *(const f32x4*)(sp);
    f32x4 s1 = *(const f32x4*)(sp + 4);
    f32x4 w0 = {(float)acc[0]*inv + s0[0], (float)acc[1]*inv + s0[1],
                (float)acc[2]*inv + s0[2], (float)acc[3]*inv + s0[3]};
    f32x4 w1 = {(float)acc[4]*inv + s1[0], (float)acc[5]*inv + s1[1],
                (float)acc[6]*inv + s1[2], (float)acc[7]*inv + s1[3]};
    float* op = out + (long)m * F2 + off;
    *(f32x4*)(op) = w0;
    *(f32x4*)(op + 4) = w1;
}

// ---------------- f16 MFMA GEMM ----------------
// C = A[M][K] @ Bt[N][K]^T. BM=64, BN=128, BK=64; 4 waves (2x2), wave tile 32x64.
// MODE 1: h1 = relu(C + bias) (f16)
// MODE 2: n<F2 -> t2[m][n] = f16(C); n>=F2 -> self[m][n-F2] = C + bias[n-F2] (f32)
template<int MODE>
__global__ __launch_bounds__(256) void hgemm_kernel(
    const f16* __restrict__ A, const f16* __restrict__ Bt,
    const float* __restrict__ bias, float* __restrict__ out_f32,
    f16* __restrict__ out_f16, int M, int N, int K)
{
    __shared__ f16 As[64][72];
    __shared__ f16 Bs[128][72];

    const int t = threadIdx.x;
    const int lane = t & 63, wave = t >> 6;
    const int wr = wave >> 1, wc = wave & 1;
    const int m0 = blockIdx.x * 64, n0 = blockIdx.y * 128;
    const int ar = t >> 2, ac = (t & 3) * 16;
    const int br = t >> 1, bc = (t & 1) * 32;

    f32x4 acc[2][4] = {};

    for (int k0 = 0; k0 < K; k0 += 64) {
        {
            const f16* ga = A + (long)(m0 + ar) * K + k0 + ac;
            bool mok = (m0 + ar) < M;
            f16x8 v0 = mok ? *(const f16x8*)(ga + 0) : (f16x8){};
            f16x8 v1 = mok ? *(const f16x8*)(ga + 8) : (f16x8){};
            *(f16x8*)&As[ar][ac + 0] = v0;
            *(f16x8*)&As[ar][ac + 8] = v1;
        }
        {
            const f16* gb = Bt + (long)(n0 + br) * K + k0 + bc;
            f16x8 v0 = *(const f16x8*)(gb + 0);
            f16x8 v1 = *(const f16x8*)(gb + 8);
            f16x8 v2 = *(const f16x8*)(gb + 16);
            f16x8 v3 = *(const f16x8*)(gb + 24);
            *(f16x8*)&Bs[br][bc + 0]  = v0;
            *(f16x8*)&Bs[br][bc + 8]  = v1;
            *(f16x8*)&Bs[br][bc + 16] = v2;
            *(f16x8*)&Bs[br][bc + 24] = v3;
        }
        __syncthreads();
        #pragma unroll
        for (int kk = 0; kk < 2; ++kk) {
            f16x8 af[2], bf[4];
            #pragma unroll
            for (int i = 0; i < 2; ++i)
                af[i] = *(const f16x8*)&As[wr * 32 + i * 16 + (lane & 15)][kk * 32 + (lane >> 4) * 8];
            #pragma unroll
            for (int j = 0; j < 4; ++j)
                bf[j] = *(const f16x8*)&Bs[wc * 64 + j * 16 + (lane & 15)][kk * 32 + (lane >> 4) * 8];
            #pragma unroll
            for (int i = 0; i < 2; ++i)
                #pragma unroll
                for (int j = 0; j < 4; ++j)
                    acc[i][j] = __builtin_amdgcn_mfma_f32_16x16x32_f16(af[i], bf[j], acc[i][j], 0, 0, 0);
        }
        __syncthreads();
    }

    // C/D layout: col = lane&15, row = (lane>>4)*4 + q  [m89-verified]
    const int cr = (lane >> 4) * 4, cc = lane & 15;
    #pragma unroll
    for (int i = 0; i < 2; ++i) {
        #pragma unroll
        for (int j = 0; j < 4; ++j) {
            int n = n0 + wc * 64 + j * 16 + cc;
            float b;
            if (MODE == 1) b = bias[n];
            else           b = (n >= F2) ? bias[n - F2] : 0.f;
            #pragma unroll
            for (int q = 0; q < 4; ++q) {
                int m = m0 + wr * 32 + i * 16 + cr + q;
                if (m >= M) continue;
                float v = acc[i][j][q];
                if (MODE == 1) {
                    out_f16[(long)m * N + n] = (f16)fmaxf(v + b, 0.f);
                } else {
                    if (n < F2) out_f16[(long)m * F2 + n] = (f16)v;
                    else        out_f32[(long)m * F2 + (n - F2)] = v + b;
                }
            }
        }
    }
}

extern "C" void kernel_launch(void* const* d_in, const int* in_sizes, int n_in,
                              void* d_out, int out_size, void* d_ws, size_t ws_size,
                              hipStream_t stream) {
    const float* x   = (const float*)d_in[0];
    const float* Ws1 = (const float*)d_in[1];
    const float* Wn1 = (const float*)d_in[2];
    const float* b1  = (const float*)d_in[3];
    const float* Ws2 = (const float*)d_in[4];
    const float* Wn2 = (const float*)d_in[5];
    const float* b2  = (const float*)d_in[6];
    const int* src   = (const int*)d_in[7];
    const int* dst   = (const int*)d_in[8];
    float* out = (float*)d_out;

    // workspace layout (bytes, 16B aligned):
    char* ws = (char*)d_ws;
    int* row_ptr = (int*)(ws);                      // 20001 i32   [0 .. 80,064)
    u16* csr16   = (u16*)(ws + 80064);              // 640000 u16  [.. 1,360,064)
    int* cursor  = (int*)(ws + 1360064);            // 20000 i32   [.. 1,440,064)
    f16* A1b     = (f16*)(ws + 1440064);            // 20000x640   [.. 27,040,064)
    f16* h1      = (f16*)(ws + 27040064);           // 20000x512   [.. 47,520,064)
    f16* t2      = (f16*)(ws + 47520064);           // 20000x256   [.. 57,760,064)
    float* selfp = (float*)(ws + 57760064);         // 20000x256 f32 [.. 78,240,064)
    f16* Wt1     = (f16*)(ws + 78240064);           // 512x640     [.. 78,895,424)
    f16* Wt2cat  = (f16*)(ws + 78895424);           // 512x512     [.. 79,419,712)

    // ---- fused prep (conv_x | Wt1 | Wt2cat | count) + CSR build ----
    hipMemsetAsync(cursor, 0, NN * sizeof(int), stream);
    prep_all_kernel<<<11054, 256, 0, stream>>>(x, Ws1, Wn1, Ws2, Wn2, dst,
                                               A1b, Wt1, Wt2cat, cursor);
    scan_kernel<<<1, 1024, 0, stream>>>(cursor, row_ptr, cursor);
    fill_kernel<<<(NE + 255) / 256, 256, 0, stream>>>(src, dst, cursor, csr16);

    // ---- layer 1: merged gather (32-feat windows), concat-GEMM + relu ----
    gather1_kernel<<<10 * 313, 256, 0, stream>>>(row_ptr, csr16, A1b);
    dim3 g1((NN + 63) / 64, F1 / 128);
    hgemm_kernel<1><<<g1, 256, 0, stream>>>(A1b, Wt1, b1, nullptr, h1, NN, F1, KP1);

    // ---- layer 2: fused [t2 | self] GEMM, then merged gather+add ----
    dim3 g2((NN + 63) / 64, (2 * F2) / 128);
    hgemm_kernel<2><<<g2, 256, 0, stream>>>(h1, Wt2cat, b2, selfp, t2, NN, 2 * F2, F1);
    gather2_kernel<<<8 * 313, 256, 0, stream>>>(row_ptr, csr16, t2, selfp, out);
}